// Round 12
// baseline (68.643 us; speedup 1.0000x reference)
//
#include <hip/hip_runtime.h>
#include <hip/hip_bf16.h>

typedef __attribute__((ext_vector_type(8))) short short8;
typedef __attribute__((ext_vector_type(4))) float f32x4;
typedef __attribute__((ext_vector_type(16))) float f32x16;

#define MFMA16(a, b, c) __builtin_amdgcn_mfma_f32_16x16x32_bf16((a), (b), (c), 0, 0, 0)
#define MFMA32(a, b, c) __builtin_amdgcn_mfma_f32_32x32x16_bf16((a), (b), (c), 0, 0, 0)

__device__ __forceinline__ unsigned short f2bf(float f) {
  union { float f; unsigned int u; } v; v.f = f;
  unsigned int u = v.u;
  unsigned int r = u + 0x7FFFu + ((u >> 16) & 1u);  // RNE
  return (unsigned short)(r >> 16);
}

// packed pair: low 16 = bf16(a), high 16 = bf16(b) -> v_cvt_pk_bf16_f32
__device__ __forceinline__ unsigned int f2bf2(float a, float b) {
  __hip_bfloat162 h2 = __float22bfloat162_rn(make_float2(a, b));
  union { __hip_bfloat162 h; unsigned int u; } cv; cv.h = h2;
  return cv.u;
}

// ---------------------------------------------------------------------------
// k0: W -> W3t bf16 frag-linear for 32x32x16 MFMA B-frags (R11, validated).
//   chunk j = (s2*6 + c)*64 + l;  lane l holds W^T[32c + (l&31)][16*s2+8*(l>>5)..+7]
// Step ks owns the contiguous chunk range [ks*768, (ks+1)*768).
// ---------------------------------------------------------------------------
__global__ void wconv_kernel(const float* __restrict__ Wq, const float* __restrict__ Wk,
                             const float* __restrict__ Wv, unsigned short* __restrict__ W3t) {
  int j = blockIdx.x * 128 + threadIdx.x;  // 0..9215 (uint4 chunks)
  int s2 = j / 384;
  int r = j - s2 * 384;
  int c = r >> 6, l = r & 63;
  int col = 32 * c + (l & 31);             // 0..191 across Q|K|V
  int k = 16 * s2 + 8 * (l >> 5);
  const float* src = (col < 64) ? Wq : ((col < 128) ? Wk : Wv);
  int sc = col & 63;
  float e[8];
#pragma unroll
  for (int i = 0; i < 8; ++i) e[i] = src[(k + i) * 64 + sc];
  uint4 u;
  u.x = f2bf2(e[0], e[1]); u.y = f2bf2(e[2], e[3]);
  u.z = f2bf2(e[4], e[5]); u.w = f2bf2(e[6], e[7]);
  *(uint4*)&W3t[j * 8] = u;
}

// ---------------------------------------------------------------------------
// k1: QKV projection. 512 blocks x 256 thr (4 waves). LDS = 24 KB only
// (W double-buffer) -> 2 blocks/CU co-resident; their barrier stalls overlap.
// Wave w: rows m0+32w..+31 x all 192 cols, 32x32x16 MFMA, acc 6 x f32x16.
// x: direct global->reg, depth-2 prefetch. W: reg-staged dbuf, 1 barrier/step.
// Writes Qg, Kg row-major bf16 [65536][64]; Vtg bf16 [256 b][64 h][256 tok].
// ---------------------------------------------------------------------------
__global__ __launch_bounds__(256) void proj_kernel(
    const float* __restrict__ x, const unsigned short* __restrict__ W3t,
    unsigned short* __restrict__ Qg, unsigned short* __restrict__ Kg,
    unsigned short* __restrict__ Vtg) {
  __shared__ unsigned short wl[2][6144];  // 12 KB per buffer (768 x 16B chunks)
  const int tid = threadIdx.x;
  const int w = tid >> 6, lane = tid & 63;
  const int l31 = lane & 31, h = lane >> 5;
  const long m0 = (long)blockIdx.x * 128;

  f32x16 acc[6];
#pragma unroll
  for (int j = 0; j < 6; ++j)
#pragma unroll
    for (int r = 0; r < 16; ++r) acc[j][r] = 0.f;

  // x source: lane owns row m0+32w+l31; per step floats 8h..8h+7 and 16+8h..
  const float* xrow = x + (m0 + 32 * w + l31) * 384 + 8 * h;

  float4 xsA[4], xsB[4];    // x regs for even/odd steps
  uint4 wregA[3], wregB[3]; // W regs for even/odd steps (chunk tid + i*256)

  auto LX = [&](float4* d, int s) {
    const float* p = xrow + 32 * s;
    d[0] = *(const float4*)&p[0];
    d[1] = *(const float4*)&p[4];
    d[2] = *(const float4*)&p[16];
    d[3] = *(const float4*)&p[20];
  };
  auto LW = [&](uint4* d, int s) {
    d[0] = *(const uint4*)&W3t[((long)s * 768 + tid) * 8];
    d[1] = *(const uint4*)&W3t[((long)s * 768 + tid + 256) * 8];
    d[2] = *(const uint4*)&W3t[((long)s * 768 + tid + 512) * 8];
  };
  auto WW = [&](unsigned short* buf, const uint4* r) {
    *(uint4*)&buf[tid * 8] = r[0];
    *(uint4*)&buf[(tid + 256) * 8] = r[1];
    *(uint4*)&buf[(tid + 512) * 8] = r[2];
  };
  auto COMPUTE = [&](const unsigned short* wb, const float4* c) {
    uint4 a0u, a1u;
    a0u.x = f2bf2(c[0].x, c[0].y); a0u.y = f2bf2(c[0].z, c[0].w);
    a0u.z = f2bf2(c[1].x, c[1].y); a0u.w = f2bf2(c[1].z, c[1].w);
    a1u.x = f2bf2(c[2].x, c[2].y); a1u.y = f2bf2(c[2].z, c[2].w);
    a1u.z = f2bf2(c[3].x, c[3].y); a1u.w = f2bf2(c[3].z, c[3].w);
    union { uint4 u; short8 s8; } av0, av1;
    av0.u = a0u; av1.u = a1u;
    const unsigned short* base = wb + lane * 8;
#pragma unroll
    for (int ct = 0; ct < 6; ++ct) {
      short8 b0 = *(const short8*)&base[ct * 512];          // kk=0
      acc[ct] = MFMA32(av0.s8, b0, acc[ct]);
      short8 b1 = *(const short8*)&base[3072 + ct * 512];   // kk=1
      acc[ct] = MFMA32(av1.s8, b1, acc[ct]);
    }
  };

  // prologue: steps 0,1 in regs; buf0 written
  LX(xsA, 0); LW(wregA, 0);
  WW(wl[0], wregA);
  LX(xsB, 1); LW(wregB, 1);
  __syncthreads();

  // main loop: step pairs (even: buf0/A, odd: buf1/B); 1 barrier per step
#pragma unroll
  for (int kp = 0; kp < 6; ++kp) {
    // even step s = 2kp
    COMPUTE(wl[0], xsA);
    if (kp < 5) { LX(xsA, 2 * kp + 2); LW(wregA, 2 * kp + 2); }
    WW(wl[1], wregB);                       // W for step 2kp+1
    __syncthreads();
    // odd step s = 2kp+1
    COMPUTE(wl[1], xsB);
    if (kp < 5) {
      LX(xsB, 2 * kp + 3); LW(wregB, 2 * kp + 3);
      WW(wl[0], wregA);                     // W for step 2kp+2
    }
    __syncthreads();
  }

  // ---- epilogue: D layout col = 32ct + l31, row = (r&3) + 8*(r>>2) + 4h ----
#pragma unroll
  for (int ct = 0; ct < 6; ++ct) {
    const int C = 32 * ct + l31;
    if (ct < 2) {  // Q cols 0..63
#pragma unroll
      for (int r = 0; r < 16; ++r) {
        long row = m0 + 32 * w + (r & 3) + 8 * (r >> 2) + 4 * h;
        Qg[row * 64 + C] = f2bf(acc[ct][r]);
      }
    } else if (ct < 4) {  // K cols 64..127
      const int cc = C - 64;
#pragma unroll
      for (int r = 0; r < 16; ++r) {
        long row = m0 + 32 * w + (r & 3) + 8 * (r >> 2) + 4 * h;
        Kg[row * 64 + cc] = f2bf(acc[ct][r]);
      }
    } else {  // V cols 128..191 -> V^T[b][h][tok], 4-token packs
      const int hh = C - 128;
      const long bb = m0 >> 8;
#pragma unroll
      for (int rq = 0; rq < 4; ++rq) {
        int tok = (int)(m0 & 255) + 32 * w + 8 * rq + 4 * h;
        uint2 pk;
        pk.x = f2bf2(acc[ct][4 * rq + 0], acc[ct][4 * rq + 1]);
        pk.y = f2bf2(acc[ct][4 * rq + 2], acc[ct][4 * rq + 3]);
        *(uint2*)&Vtg[(bb * 64 + hh) * 256 + tok] = pk;
      }
    }
  }
}

// ---------------------------------------------------------------------------
// k2: causal attention. 256 blocks x 512 thr (8 waves). Dynamic LDS 80896 B:
//   Kl [256][72] @0 | Vl [64][264] @18432 | Pb 8 x [16][40] @35328 (ush)
// Wave w owns tiles {w, 15-w}; swapped QK^T + online softmax (R11 body,
// validated); Q read per-lane from global (L2/L3-hot).
// ---------------------------------------------------------------------------
__global__ __launch_bounds__(512) void attn_kernel(
    const unsigned short* __restrict__ Qg, const unsigned short* __restrict__ Kg,
    const unsigned short* __restrict__ Vtg, float* __restrict__ out) {
  extern __shared__ unsigned short sm[];
  unsigned short* Kl = sm;
  unsigned short* Vl = sm + 18432;
  const int tid = threadIdx.x;
  const int w = tid >> 6, lane = tid & 63, g = lane >> 4, q = lane & 15;
  const int b = blockIdx.x;
  const unsigned short* Kgb = Kg + (long)b * 16384;
  const unsigned short* Vgb = Vtg + (long)b * 16384;

  // stage K row-major (padded 72) and V^T h-major (padded 264)
#pragma unroll
  for (int it = 0; it < 4; ++it) {
    int i = tid + it * 512;
    int tok = i >> 3, k0 = (i & 7) * 8;
    *(uint4*)&Kl[tok * 72 + k0] = *(const uint4*)&Kgb[tok * 64 + k0];
  }
#pragma unroll
  for (int it = 0; it < 4; ++it) {
    int i = tid + it * 512;
    int hh = i >> 5, t0 = (i & 31) * 8;
    *(uint4*)&Vl[hh * 264 + t0] = *(const uint4*)&Vgb[hh * 256 + t0];
  }
  __syncthreads();

  unsigned short* Pb = sm + 35328 + w * 640;  // per-wave [16][40] P buffer
  const float SCL = 0.125f * 1.4426950408889634f;  // H^-0.5 * log2(e)
  const f32x4 zf = {0.f, 0.f, 0.f, 0.f};

#pragma unroll
  for (int ti = 0; ti < 2; ++ti) {
    const int t = ti ? (15 - w) : w;

    // Q as B-operand: lane (q,g) holds Q[b*256+16t+q][8g.. / 32+8g..]
    const unsigned short* Qrow = Qg + ((long)b * 256 + 16 * t + q) * 64;
    short8 aq0 = *(const short8*)&Qrow[g * 8];
    short8 aq1 = *(const short8*)&Qrow[32 + g * 8];

    f32x4 o[4];
#pragma unroll
    for (int ct = 0; ct < 4; ++ct) o[ct] = zf;
    float m = -1e30f;
    float lsum = 0.f;

    const int KS = (t >> 1) + 1;  // wave-uniform trip count
    for (int ks = 0; ks < KS; ++ks) {
      const int j0 = 2 * ks, j1 = 2 * ks + 1;
      const bool has1 = (j1 <= t);
      // K as A-operand: D[row=4g+jr][col=q] = S[K-token 16j+4g+jr][Q-row 16t+q]
      short8 ka0 = *(const short8*)&Kl[(16 * j0 + q) * 72 + g * 8];
      short8 ka1 = *(const short8*)&Kl[(16 * j0 + q) * 72 + 32 + g * 8];
      f32x4 s0 = MFMA16(ka0, aq0, zf);
      s0 = MFMA16(ka1, aq1, s0);
      f32x4 s1 = zf;
      if (has1) {
        short8 kb0 = *(const short8*)&Kl[(16 * j1 + q) * 72 + g * 8];
        short8 kb1 = *(const short8*)&Kl[(16 * j1 + q) * 72 + 32 + g * 8];
        s1 = MFMA16(kb0, aq0, zf);
        s1 = MFMA16(kb1, aq1, s1);
      }
      float v[8];
#pragma unroll
      for (int jr = 0; jr < 4; ++jr) {
        float aa = s0[jr] * SCL;
        if (j0 == t && 4 * g + jr > q) aa = -1e30f;  // causal (diag tile)
        v[jr] = aa;
        float cc = has1 ? s1[jr] * SCL : -1e30f;
        if (has1 && j1 == t && 4 * g + jr > q) cc = -1e30f;
        v[4 + jr] = cc;
      }
      float mloc = fmaxf(fmaxf(fmaxf(v[0], v[1]), fmaxf(v[2], v[3])),
                         fmaxf(fmaxf(v[4], v[5]), fmaxf(v[6], v[7])));
      mloc = fmaxf(mloc, __shfl_xor(mloc, 16));
      mloc = fmaxf(mloc, __shfl_xor(mloc, 32));
      float mnew = fmaxf(m, mloc);
      float f = exp2f(m - mnew);  // factor for q-row q (this lane's row)
      m = mnew;
      float p[8];
      float ls = 0.f;
#pragma unroll
      for (int i = 0; i < 8; ++i) { p[i] = exp2f(v[i] - mnew); ls += p[i]; }
      lsum = lsum * f + ls;
      // o[ct][jr] accumulates Q-row 4g+jr -> fetch that row's factor
#pragma unroll
      for (int jr = 0; jr < 4; ++jr) {
        float fr = __shfl(f, 4 * g + jr);
        o[0][jr] *= fr; o[1][jr] *= fr; o[2][jr] *= fr; o[3][jr] *= fr;
      }
      // P store (row q, cols 4g..4g+3 of each 16-tile) then transposed read
      uint2 pa; pa.x = f2bf2(p[0], p[1]); pa.y = f2bf2(p[2], p[3]);
      *(uint2*)&Pb[q * 40 + 4 * g] = pa;
      uint2 pc; pc.x = f2bf2(p[4], p[5]); pc.y = f2bf2(p[6], p[7]);
      *(uint2*)&Pb[q * 40 + 16 + 4 * g] = pc;
      short8 ap = *(const short8*)&Pb[q * 40 + g * 8];
#pragma unroll
      for (int ct = 0; ct < 4; ++ct) {
        short8 bv = *(const short8*)&Vl[(16 * ct + q) * 264 + ks * 32 + g * 8];
        o[ct] = MFMA16(ap, bv, o[ct]);
      }
    }

    // final row-sum: fold g-partials (row q), then fetch row 4g+jr's sum
    lsum += __shfl_xor(lsum, 16);
    lsum += __shfl_xor(lsum, 32);
    float linv[4];
#pragma unroll
    for (int jr = 0; jr < 4; ++jr) linv[jr] = 1.0f / __shfl(lsum, 4 * g + jr);

    const long rowbase = (long)b * 256 + 16 * t;
#pragma unroll
    for (int jr = 0; jr < 4; ++jr) {
#pragma unroll
      for (int ct = 0; ct < 4; ++ct) {
        out[(rowbase + 4 * g + jr) * 64 + 16 * ct + q] = o[ct][jr] * linv[jr];
      }
    }
  }
}

// ---------------------------------------------------------------------------
extern "C" void kernel_launch(void* const* d_in, const int* in_sizes, int n_in,
                              void* d_out, int out_size, void* d_ws, size_t ws_size,
                              hipStream_t stream) {
  const float* x  = (const float*)d_in[0];
  const float* Wq = (const float*)d_in[1];
  const float* Wk = (const float*)d_in[2];
  const float* Wv = (const float*)d_in[3];
  float* out = (float*)d_out;

  char* ws = (char*)d_ws;
  unsigned short* W3t = (unsigned short*)ws;                        // 147,456 B
  unsigned short* Qg  = (unsigned short*)(ws + 147456);             // 8,388,608 B
  unsigned short* Kg  = (unsigned short*)(ws + 147456 + 8388608);   // 8,388,608 B
  unsigned short* Vtg = (unsigned short*)(ws + 147456 + 16777216);  // 8,388,608 B

  hipFuncSetAttribute((const void*)attn_kernel,
                      hipFuncAttributeMaxDynamicSharedMemorySize, 80896);

  wconv_kernel<<<72, 128, 0, stream>>>(Wq, Wk, Wv, W3t);
  proj_kernel<<<512, 256, 0, stream>>>(x, W3t, Qg, Kg, Vtg);
  attn_kernel<<<256, 512, 80896, stream>>>(Qg, Kg, Vtg, out);
}

// Round 13
// 68.131 us; speedup vs baseline: 1.0075x; 1.0075x over previous
//
#include <hip/hip_runtime.h>
#include <hip/hip_bf16.h>

typedef __attribute__((ext_vector_type(8))) short short8;
typedef __attribute__((ext_vector_type(4))) float f32x4;
typedef __attribute__((ext_vector_type(16))) float f32x16;

#define MFMA16(a, b, c) __builtin_amdgcn_mfma_f32_16x16x32_bf16((a), (b), (c), 0, 0, 0)
#define MFMA32(a, b, c) __builtin_amdgcn_mfma_f32_32x32x16_bf16((a), (b), (c), 0, 0, 0)

__device__ __forceinline__ unsigned short f2bf(float f) {
  union { float f; unsigned int u; } v; v.f = f;
  unsigned int u = v.u;
  unsigned int r = u + 0x7FFFu + ((u >> 16) & 1u);  // RNE
  return (unsigned short)(r >> 16);
}

// packed pair: low 16 = bf16(a), high 16 = bf16(b) -> v_cvt_pk_bf16_f32
__device__ __forceinline__ unsigned int f2bf2(float a, float b) {
  __hip_bfloat162 h2 = __float22bfloat162_rn(make_float2(a, b));
  union { __hip_bfloat162 h; unsigned int u; } cv; cv.h = h2;
  return cv.u;
}

// ---------------------------------------------------------------------------
// k0: W -> W3t bf16 frag-linear for 32x32x16 MFMA B-frags (validated R11/R12).
//   chunk j = (s2*6 + c)*64 + l;  lane l holds W^T[32c+(l&31)][16*s2+8*(l>>5)..+7]
// ---------------------------------------------------------------------------
__global__ void wconv_kernel(const float* __restrict__ Wq, const float* __restrict__ Wk,
                             const float* __restrict__ Wv, unsigned short* __restrict__ W3t) {
  int j = blockIdx.x * 128 + threadIdx.x;  // 0..9215 (uint4 chunks)
  int s2 = j / 384;
  int r = j - s2 * 384;
  int c = r >> 6, l = r & 63;
  int col = 32 * c + (l & 31);             // 0..191 across Q|K|V
  int k = 16 * s2 + 8 * (l >> 5);
  const float* src = (col < 64) ? Wq : ((col < 128) ? Wk : Wv);
  int sc = col & 63;
  float e[8];
#pragma unroll
  for (int i = 0; i < 8; ++i) e[i] = src[(k + i) * 64 + sc];
  uint4 u;
  u.x = f2bf2(e[0], e[1]); u.y = f2bf2(e[2], e[3]);
  u.z = f2bf2(e[4], e[5]); u.w = f2bf2(e[6], e[7]);
  *(uint4*)&W3t[j * 8] = u;
}

// ---------------------------------------------------------------------------
// k1: QKV projection. 512 blocks x 256 thr (4 waves), 24.6 KB LDS
// (-> multiple blocks/CU; independent barriers overlap stalls).
// Wave w: rows m0+32w..+31 x all 192 cols, 32x32x16 MFMA, acc 6 x f32x16.
// x: direct global->reg depth-2 prefetch. W: reg-staged dbuf, 1 barrier/step.
// EPILOGUE: 3-round LDS bounce (reuses dead W buffer) so ALL global stores
// are contiguous uint4 runs (R12's 8B-scatter caused 3.7x write amplification
// -> 93 MB HBM writes; this restores the 25.2 MB logical).
// ---------------------------------------------------------------------------
__global__ __launch_bounds__(256) void proj_kernel(
    const float* __restrict__ x, const unsigned short* __restrict__ W3t,
    unsigned short* __restrict__ Qg, unsigned short* __restrict__ Kg,
    unsigned short* __restrict__ Vtg) {
  __shared__ __align__(16) unsigned short wl[2][6144];  // 24576 B
  const int tid = threadIdx.x;
  const int w = tid >> 6, lane = tid & 63;
  const int l31 = lane & 31, h = lane >> 5;
  const long m0 = (long)blockIdx.x * 128;

  f32x16 acc[6];
#pragma unroll
  for (int j = 0; j < 6; ++j)
#pragma unroll
    for (int r = 0; r < 16; ++r) acc[j][r] = 0.f;

  // x source: lane owns row m0+32w+l31; per step floats 8h..8h+7 and 16+8h..
  const float* xrow = x + (m0 + 32 * w + l31) * 384 + 8 * h;

  float4 xsA[4], xsB[4];    // x regs for even/odd steps
  uint4 wregA[3], wregB[3]; // W regs for even/odd steps (chunk tid + i*256)

  auto LX = [&](float4* d, int s) {
    const float* p = xrow + 32 * s;
    d[0] = *(const float4*)&p[0];
    d[1] = *(const float4*)&p[4];
    d[2] = *(const float4*)&p[16];
    d[3] = *(const float4*)&p[20];
  };
  auto LW = [&](uint4* d, int s) {
    d[0] = *(const uint4*)&W3t[((long)s * 768 + tid) * 8];
    d[1] = *(const uint4*)&W3t[((long)s * 768 + tid + 256) * 8];
    d[2] = *(const uint4*)&W3t[((long)s * 768 + tid + 512) * 8];
  };
  auto WW = [&](unsigned short* buf, const uint4* r) {
    *(uint4*)&buf[tid * 8] = r[0];
    *(uint4*)&buf[(tid + 256) * 8] = r[1];
    *(uint4*)&buf[(tid + 512) * 8] = r[2];
  };
  auto COMPUTE = [&](const unsigned short* wb, const float4* c) {
    uint4 a0u, a1u;
    a0u.x = f2bf2(c[0].x, c[0].y); a0u.y = f2bf2(c[0].z, c[0].w);
    a0u.z = f2bf2(c[1].x, c[1].y); a0u.w = f2bf2(c[1].z, c[1].w);
    a1u.x = f2bf2(c[2].x, c[2].y); a1u.y = f2bf2(c[2].z, c[2].w);
    a1u.z = f2bf2(c[3].x, c[3].y); a1u.w = f2bf2(c[3].z, c[3].w);
    union { uint4 u; short8 s8; } av0, av1;
    av0.u = a0u; av1.u = a1u;
    const unsigned short* base = wb + lane * 8;
#pragma unroll
    for (int ct = 0; ct < 6; ++ct) {
      short8 b0 = *(const short8*)&base[ct * 512];          // kk=0
      acc[ct] = MFMA32(av0.s8, b0, acc[ct]);
      short8 b1 = *(const short8*)&base[3072 + ct * 512];   // kk=1
      acc[ct] = MFMA32(av1.s8, b1, acc[ct]);
    }
  };

  // prologue: steps 0,1 in regs; buf0 written
  LX(xsA, 0); LW(wregA, 0);
  WW(wl[0], wregA);
  LX(xsB, 1); LW(wregB, 1);
  __syncthreads();

  // main loop: step pairs (even: buf0/A, odd: buf1/B); 1 barrier per step
#pragma unroll
  for (int kp = 0; kp < 6; ++kp) {
    COMPUTE(wl[0], xsA);
    if (kp < 5) { LX(xsA, 2 * kp + 2); LW(wregA, 2 * kp + 2); }
    WW(wl[1], wregB);
    __syncthreads();
    COMPUTE(wl[1], xsB);
    if (kp < 5) {
      LX(xsB, 2 * kp + 3); LW(wregB, 2 * kp + 3);
      WW(wl[0], wregA);
    }
    __syncthreads();
  }

  // ---- epilogue: 3-round LDS bounce -> contiguous global writes ----
  // D layout (32x32 MFMA): col = 32ct + l31, row_local = (r&3)+8*(r>>2)+4h
  unsigned short* buf = &wl[0][0];

  // Round Q (acc 0,1) and Round K (acc 2,3): buf as [128 rows][72 pad]
#pragma unroll
  for (int round = 0; round < 2; ++round) {
    __syncthreads();  // previous buf use complete
#pragma unroll
    for (int cc = 0; cc < 2; ++cc) {
      const int ct = 2 * round + cc;
#pragma unroll
      for (int r = 0; r < 16; ++r) {
        int rowl = 32 * w + (r & 3) + 8 * (r >> 2) + 4 * h;
        buf[rowl * 72 + 32 * cc + l31] = f2bf(acc[ct][r]);
      }
    }
    __syncthreads();
    unsigned short* dst = round ? Kg : Qg;
#pragma unroll
    for (int i = 0; i < 4; ++i) {
      int c = tid + i * 256;          // 0..1023
      int rowl = c >> 3, c8 = (c & 7) * 8;
      uint4 v = *(const uint4*)&buf[rowl * 72 + c8];
      *(uint4*)&dst[(m0 + rowl) * 64 + c8] = v;  // 16KB contiguous per block
    }
  }

  // Round V (acc 4,5): buf as [64 h][136 pad] holding V^T chunk [64][128 tok]
  __syncthreads();
#pragma unroll
  for (int cc = 0; cc < 2; ++cc) {
    const int ct = 4 + cc;
    const int hh = 32 * cc + l31;
#pragma unroll
    for (int rq = 0; rq < 4; ++rq) {
      int tokloc = 32 * w + 8 * rq + 4 * h;
      uint2 pk;
      pk.x = f2bf2(acc[ct][4 * rq + 0], acc[ct][4 * rq + 1]);
      pk.y = f2bf2(acc[ct][4 * rq + 2], acc[ct][4 * rq + 3]);
      *(uint2*)&buf[hh * 136 + tokloc] = pk;
    }
  }
  __syncthreads();
  {
    const long bb = m0 >> 8;
    const int tokbase = (int)(m0 & 255);
#pragma unroll
    for (int i = 0; i < 4; ++i) {
      int c = tid + i * 256;          // 0..1023
      int hh = c >> 4, t8 = (c & 15) * 8;
      uint4 v = *(const uint4*)&buf[hh * 136 + t8];
      *(uint4*)&Vtg[(bb * 64 + hh) * 256 + tokbase + t8] = v;  // 256B runs
    }
  }
}

// ---------------------------------------------------------------------------
// k2: causal attention. 256 blocks x 512 thr (8 waves). Dynamic LDS 80896 B.
//   Kl [256][72] @0 | Vl [64][264] @18432 | Pb 8 x [16][40] @35328 (ush)
// Wave w owns tiles {w, 15-w}; swapped QK^T + online softmax (validated body);
// Q read per-lane from global (L2/L3-hot).
// ---------------------------------------------------------------------------
__global__ __launch_bounds__(512) void attn_kernel(
    const unsigned short* __restrict__ Qg, const unsigned short* __restrict__ Kg,
    const unsigned short* __restrict__ Vtg, float* __restrict__ out) {
  extern __shared__ unsigned short sm[];
  unsigned short* Kl = sm;
  unsigned short* Vl = sm + 18432;
  const int tid = threadIdx.x;
  const int w = tid >> 6, lane = tid & 63, g = lane >> 4, q = lane & 15;
  const int b = blockIdx.x;
  const unsigned short* Kgb = Kg + (long)b * 16384;
  const unsigned short* Vgb = Vtg + (long)b * 16384;

  // stage K row-major (padded 72) and V^T h-major (padded 264)
#pragma unroll
  for (int it = 0; it < 4; ++it) {
    int i = tid + it * 512;
    int tok = i >> 3, k0 = (i & 7) * 8;
    *(uint4*)&Kl[tok * 72 + k0] = *(const uint4*)&Kgb[tok * 64 + k0];
  }
#pragma unroll
  for (int it = 0; it < 4; ++it) {
    int i = tid + it * 512;
    int hh = i >> 5, t0 = (i & 31) * 8;
    *(uint4*)&Vl[hh * 264 + t0] = *(const uint4*)&Vgb[hh * 256 + t0];
  }
  __syncthreads();

  unsigned short* Pb = sm + 35328 + w * 640;  // per-wave [16][40] P buffer
  const float SCL = 0.125f * 1.4426950408889634f;  // H^-0.5 * log2(e)
  const f32x4 zf = {0.f, 0.f, 0.f, 0.f};

#pragma unroll
  for (int ti = 0; ti < 2; ++ti) {
    const int t = ti ? (15 - w) : w;

    // Q as B-operand: lane (q,g) holds Q[b*256+16t+q][8g.. / 32+8g..]
    const unsigned short* Qrow = Qg + ((long)b * 256 + 16 * t + q) * 64;
    short8 aq0 = *(const short8*)&Qrow[g * 8];
    short8 aq1 = *(const short8*)&Qrow[32 + g * 8];

    f32x4 o[4];
#pragma unroll
    for (int ct = 0; ct < 4; ++ct) o[ct] = zf;
    float m = -1e30f;
    float lsum = 0.f;

    const int KS = (t >> 1) + 1;  // wave-uniform trip count
    for (int ks = 0; ks < KS; ++ks) {
      const int j0 = 2 * ks, j1 = 2 * ks + 1;
      const bool has1 = (j1 <= t);
      // K as A-operand: D[row=4g+jr][col=q] = S[K-token 16j+4g+jr][Q-row 16t+q]
      short8 ka0 = *(const short8*)&Kl[(16 * j0 + q) * 72 + g * 8];
      short8 ka1 = *(const short8*)&Kl[(16 * j0 + q) * 72 + 32 + g * 8];
      f32x4 s0 = MFMA16(ka0, aq0, zf);
      s0 = MFMA16(ka1, aq1, s0);
      f32x4 s1 = zf;
      if (has1) {
        short8 kb0 = *(const short8*)&Kl[(16 * j1 + q) * 72 + g * 8];
        short8 kb1 = *(const short8*)&Kl[(16 * j1 + q) * 72 + 32 + g * 8];
        s1 = MFMA16(kb0, aq0, zf);
        s1 = MFMA16(kb1, aq1, s1);
      }
      float v[8];
#pragma unroll
      for (int jr = 0; jr < 4; ++jr) {
        float aa = s0[jr] * SCL;
        if (j0 == t && 4 * g + jr > q) aa = -1e30f;  // causal (diag tile)
        v[jr] = aa;
        float cc = has1 ? s1[jr] * SCL : -1e30f;
        if (has1 && j1 == t && 4 * g + jr > q) cc = -1e30f;
        v[4 + jr] = cc;
      }
      float mloc = fmaxf(fmaxf(fmaxf(v[0], v[1]), fmaxf(v[2], v[3])),
                         fmaxf(fmaxf(v[4], v[5]), fmaxf(v[6], v[7])));
      mloc = fmaxf(mloc, __shfl_xor(mloc, 16));
      mloc = fmaxf(mloc, __shfl_xor(mloc, 32));
      float mnew = fmaxf(m, mloc);
      float f = exp2f(m - mnew);  // factor for q-row q (this lane's row)
      m = mnew;
      float p[8];
      float ls = 0.f;
#pragma unroll
      for (int i = 0; i < 8; ++i) { p[i] = exp2f(v[i] - mnew); ls += p[i]; }
      lsum = lsum * f + ls;
      // o[ct][jr] accumulates Q-row 4g+jr -> fetch that row's factor
#pragma unroll
      for (int jr = 0; jr < 4; ++jr) {
        float fr = __shfl(f, 4 * g + jr);
        o[0][jr] *= fr; o[1][jr] *= fr; o[2][jr] *= fr; o[3][jr] *= fr;
      }
      // P store (row q, cols 4g..4g+3 of each 16-tile) then transposed read
      uint2 pa; pa.x = f2bf2(p[0], p[1]); pa.y = f2bf2(p[2], p[3]);
      *(uint2*)&Pb[q * 40 + 4 * g] = pa;
      uint2 pc; pc.x = f2bf2(p[4], p[5]); pc.y = f2bf2(p[6], p[7]);
      *(uint2*)&Pb[q * 40 + 16 + 4 * g] = pc;
      short8 ap = *(const short8*)&Pb[q * 40 + g * 8];
#pragma unroll
      for (int ct = 0; ct < 4; ++ct) {
        short8 bv = *(const short8*)&Vl[(16 * ct + q) * 264 + ks * 32 + g * 8];
        o[ct] = MFMA16(ap, bv, o[ct]);
      }
    }

    // final row-sum: fold g-partials (row q), then fetch row 4g+jr's sum
    lsum += __shfl_xor(lsum, 16);
    lsum += __shfl_xor(lsum, 32);
    float linv[4];
#pragma unroll
    for (int jr = 0; jr < 4; ++jr) linv[jr] = 1.0f / __shfl(lsum, 4 * g + jr);

    const long rowbase = (long)b * 256 + 16 * t;
#pragma unroll
    for (int jr = 0; jr < 4; ++jr) {
#pragma unroll
      for (int ct = 0; ct < 4; ++ct) {
        out[(rowbase + 4 * g + jr) * 64 + 16 * ct + q] = o[ct][jr] * linv[jr];
      }
    }
  }
}

// ---------------------------------------------------------------------------
extern "C" void kernel_launch(void* const* d_in, const int* in_sizes, int n_in,
                              void* d_out, int out_size, void* d_ws, size_t ws_size,
                              hipStream_t stream) {
  const float* x  = (const float*)d_in[0];
  const float* Wq = (const float*)d_in[1];
  const float* Wk = (const float*)d_in[2];
  const float* Wv = (const float*)d_in[3];
  float* out = (float*)d_out;

  char* ws = (char*)d_ws;
  unsigned short* W3t = (unsigned short*)ws;                        // 147,456 B
  unsigned short* Qg  = (unsigned short*)(ws + 147456);             // 8,388,608 B
  unsigned short* Kg  = (unsigned short*)(ws + 147456 + 8388608);   // 8,388,608 B
  unsigned short* Vtg = (unsigned short*)(ws + 147456 + 16777216);  // 8,388,608 B

  hipFuncSetAttribute((const void*)attn_kernel,
                      hipFuncAttributeMaxDynamicSharedMemorySize, 80896);

  wconv_kernel<<<72, 128, 0, stream>>>(Wq, Wk, Wv, W3t);
  proj_kernel<<<512, 256, 0, stream>>>(x, W3t, Qg, Kg, Vtg);
  attn_kernel<<<256, 512, 80896, stream>>>(Qg, Kg, Vtg, out);
}

// Round 14
// 43.802 us; speedup vs baseline: 1.5671x; 1.5554x over previous
//
#include <hip/hip_runtime.h>
#include <hip/hip_bf16.h>

typedef __attribute__((ext_vector_type(8))) short short8;
typedef __attribute__((ext_vector_type(4))) float f32x4;
typedef __attribute__((ext_vector_type(16))) float f32x16;

#define MFMA16(a, b, c) __builtin_amdgcn_mfma_f32_16x16x32_bf16((a), (b), (c), 0, 0, 0)
#define MFMA32(a, b, c) __builtin_amdgcn_mfma_f32_32x32x16_bf16((a), (b), (c), 0, 0, 0)

__device__ __forceinline__ unsigned short f2bf(float f) {
  union { float f; unsigned int u; } v; v.f = f;
  unsigned int u = v.u;
  unsigned int r = u + 0x7FFFu + ((u >> 16) & 1u);  // RNE
  return (unsigned short)(r >> 16);
}

// packed pair: low 16 = bf16(a), high 16 = bf16(b) -> v_cvt_pk_bf16_f32
__device__ __forceinline__ unsigned int f2bf2(float a, float b) {
  __hip_bfloat162 h2 = __float22bfloat162_rn(make_float2(a, b));
  union { __hip_bfloat162 h; unsigned int u; } cv; cv.h = h2;
  return cv.u;
}

// ---------------------------------------------------------------------------
// k0: W -> W3t bf16 frag-linear for 32x32x16 MFMA B-frags (validated R11/R12).
//   chunk j = (s2*6 + c)*64 + l;  lane l holds W^T[32c+(l&31)][16*s2+8*(l>>5)..+7]
// ---------------------------------------------------------------------------
__global__ void wconv_kernel(const float* __restrict__ Wq, const float* __restrict__ Wk,
                             const float* __restrict__ Wv, unsigned short* __restrict__ W3t) {
  int j = blockIdx.x * 128 + threadIdx.x;  // 0..9215 (uint4 chunks)
  int s2 = j / 384;
  int r = j - s2 * 384;
  int c = r >> 6, l = r & 63;
  int col = 32 * c + (l & 31);             // 0..191 across Q|K|V
  int k = 16 * s2 + 8 * (l >> 5);
  const float* src = (col < 64) ? Wq : ((col < 128) ? Wk : Wv);
  int sc = col & 63;
  float e[8];
#pragma unroll
  for (int i = 0; i < 8; ++i) e[i] = src[(k + i) * 64 + sc];
  uint4 u;
  u.x = f2bf2(e[0], e[1]); u.y = f2bf2(e[2], e[3]);
  u.z = f2bf2(e[4], e[5]); u.w = f2bf2(e[6], e[7]);
  *(uint4*)&W3t[j * 8] = u;
}

// ---------------------------------------------------------------------------
// k1: QKV projection. 512 blocks x 256 thr (4 waves).
// __launch_bounds__(256, 2): 2 waves/EU min -> 256 unified-VGPR budget/wave.
// Live state ~180 regs (acc 96 + x 32 + W 24 + addr) FITS -> no spill.
// (R12/R13's 93 MB WRITE_SIZE was scratch spill from the default reg cap;
//  stores were already coalesced.)
// Wave w: rows m0+32w..+31 x all 192 cols, 32x32x16 MFMA, acc 6 x f32x16.
// x: direct global->reg depth-2 prefetch (named regs, no arrays).
// W: reg-staged LDS double-buffer, 1 barrier/step.
// Epilogue: 3-round LDS bounce -> fully contiguous global stores.
// ---------------------------------------------------------------------------
__global__ __launch_bounds__(256, 2) void proj_kernel(
    const float* __restrict__ x, const unsigned short* __restrict__ W3t,
    unsigned short* __restrict__ Qg, unsigned short* __restrict__ Kg,
    unsigned short* __restrict__ Vtg) {
  __shared__ __align__(16) unsigned short wl[2][6144];  // 24576 B
  const int tid = threadIdx.x;
  const int w = tid >> 6, lane = tid & 63;
  const int l31 = lane & 31, h = lane >> 5;
  const long m0 = (long)blockIdx.x * 128;

  f32x16 acc[6];
#pragma unroll
  for (int j = 0; j < 6; ++j)
#pragma unroll
    for (int r = 0; r < 16; ++r) acc[j][r] = 0.f;

  // x source: lane owns row m0+32w+l31; per step floats 8h..+7 and 16+8h..+7
  const float* xrow = x + (m0 + 32 * w + l31) * 384 + 8 * h;

  float4 xa0, xa1, xa2, xa3;   // even-step x regs
  float4 xb0, xb1, xb2, xb3;   // odd-step x regs
  uint4 wa0, wa1, wa2;         // even-step W regs (chunks tid, tid+256, tid+512)
  uint4 wb0, wb1, wb2;         // odd-step W regs

#define LXA(s) { const float* p = xrow + 32 * (s); \
  xa0 = *(const float4*)&p[0];  xa1 = *(const float4*)&p[4]; \
  xa2 = *(const float4*)&p[16]; xa3 = *(const float4*)&p[20]; }
#define LXB(s) { const float* p = xrow + 32 * (s); \
  xb0 = *(const float4*)&p[0];  xb1 = *(const float4*)&p[4]; \
  xb2 = *(const float4*)&p[16]; xb3 = *(const float4*)&p[20]; }
#define LWA(s) { const unsigned short* p = &W3t[(long)(s) * 6144]; \
  wa0 = *(const uint4*)&p[tid * 8]; \
  wa1 = *(const uint4*)&p[(tid + 256) * 8]; \
  wa2 = *(const uint4*)&p[(tid + 512) * 8]; }
#define LWB(s) { const unsigned short* p = &W3t[(long)(s) * 6144]; \
  wb0 = *(const uint4*)&p[tid * 8]; \
  wb1 = *(const uint4*)&p[(tid + 256) * 8]; \
  wb2 = *(const uint4*)&p[(tid + 512) * 8]; }
#define WWA(buf) { unsigned short* d = (buf); \
  *(uint4*)&d[tid * 8] = wa0; \
  *(uint4*)&d[(tid + 256) * 8] = wa1; \
  *(uint4*)&d[(tid + 512) * 8] = wa2; }
#define WWB(buf) { unsigned short* d = (buf); \
  *(uint4*)&d[tid * 8] = wb0; \
  *(uint4*)&d[(tid + 256) * 8] = wb1; \
  *(uint4*)&d[(tid + 512) * 8] = wb2; }
#define COMP(wbuf, c0, c1, c2, c3) { \
  uint4 a0u, a1u; \
  a0u.x = f2bf2(c0.x, c0.y); a0u.y = f2bf2(c0.z, c0.w); \
  a0u.z = f2bf2(c1.x, c1.y); a0u.w = f2bf2(c1.z, c1.w); \
  a1u.x = f2bf2(c2.x, c2.y); a1u.y = f2bf2(c2.z, c2.w); \
  a1u.z = f2bf2(c3.x, c3.y); a1u.w = f2bf2(c3.z, c3.w); \
  union { uint4 u; short8 s8; } av0, av1; \
  av0.u = a0u; av1.u = a1u; \
  const unsigned short* base = (wbuf) + lane * 8; \
  _Pragma("unroll") \
  for (int ct = 0; ct < 6; ++ct) { \
    short8 b0 = *(const short8*)&base[ct * 512]; \
    acc[ct] = MFMA32(av0.s8, b0, acc[ct]); \
    short8 b1 = *(const short8*)&base[3072 + ct * 512]; \
    acc[ct] = MFMA32(av1.s8, b1, acc[ct]); \
  } }

  // prologue: steps 0,1 in regs; buf0 written
  LXA(0); LWA(0);
  WWA(&wl[0][0]);
  LXB(1); LWB(1);
  __syncthreads();

  // main loop: step pairs (even: buf0/A, odd: buf1/B); 1 barrier per step
#pragma unroll
  for (int kp = 0; kp < 6; ++kp) {
    COMP(&wl[0][0], xa0, xa1, xa2, xa3);
    if (kp < 5) { LXA(2 * kp + 2); LWA(2 * kp + 2); }
    WWB(&wl[1][0]);
    __syncthreads();
    COMP(&wl[1][0], xb0, xb1, xb2, xb3);
    if (kp < 5) {
      LXB(2 * kp + 3); LWB(2 * kp + 3);
      WWA(&wl[0][0]);
    }
    __syncthreads();
  }

  // ---- epilogue: 3-round LDS bounce -> contiguous global writes ----
  // D layout (32x32 MFMA): col = 32ct + l31, row_local = (r&3)+8*(r>>2)+4h
  unsigned short* buf = &wl[0][0];

  // Round Q (acc 0,1) and Round K (acc 2,3): buf as [128 rows][72 pad]
#pragma unroll
  for (int round = 0; round < 2; ++round) {
    __syncthreads();  // previous buf use complete
#pragma unroll
    for (int cc = 0; cc < 2; ++cc) {
      const int ct = 2 * round + cc;
#pragma unroll
      for (int r = 0; r < 16; ++r) {
        int rowl = 32 * w + (r & 3) + 8 * (r >> 2) + 4 * h;
        buf[rowl * 72 + 32 * cc + l31] = f2bf(acc[ct][r]);
      }
    }
    __syncthreads();
    unsigned short* dst = round ? Kg : Qg;
#pragma unroll
    for (int i = 0; i < 4; ++i) {
      int c = tid + i * 256;          // 0..1023
      int rowl = c >> 3, c8 = (c & 7) * 8;
      uint4 v = *(const uint4*)&buf[rowl * 72 + c8];
      *(uint4*)&dst[(m0 + rowl) * 64 + c8] = v;  // 16KB contiguous per block
    }
  }

  // Round V (acc 4,5): buf as [64 h][136 pad] holding V^T chunk [64][128 tok]
  __syncthreads();
#pragma unroll
  for (int cc = 0; cc < 2; ++cc) {
    const int ct = 4 + cc;
    const int hh = 32 * cc + l31;
#pragma unroll
    for (int rq = 0; rq < 4; ++rq) {
      int tokloc = 32 * w + 8 * rq + 4 * h;
      uint2 pk;
      pk.x = f2bf2(acc[ct][4 * rq + 0], acc[ct][4 * rq + 1]);
      pk.y = f2bf2(acc[ct][4 * rq + 2], acc[ct][4 * rq + 3]);
      *(uint2*)&buf[hh * 136 + tokloc] = pk;
    }
  }
  __syncthreads();
  {
    const long bb = m0 >> 8;
    const int tokbase = (int)(m0 & 255);
#pragma unroll
    for (int i = 0; i < 4; ++i) {
      int c = tid + i * 256;          // 0..1023
      int hh = c >> 4, t8 = (c & 15) * 8;
      uint4 v = *(const uint4*)&buf[hh * 136 + t8];
      *(uint4*)&Vtg[(bb * 64 + hh) * 256 + tokbase + t8] = v;  // 256B runs
    }
  }
#undef LXA
#undef LXB
#undef LWA
#undef LWB
#undef WWA
#undef WWB
#undef COMP
}

// ---------------------------------------------------------------------------
// k2: causal attention. 256 blocks x 512 thr (8 waves). Dynamic LDS 80896 B.
//   Kl [256][72] @0 | Vl [64][264] @18432 | Pb 8 x [16][40] @35328 (ush)
// Wave w owns tiles {w, 15-w}; swapped QK^T + online softmax (validated body);
// Q read per-lane from global (L2/L3-hot).
// ---------------------------------------------------------------------------
__global__ __launch_bounds__(512) void attn_kernel(
    const unsigned short* __restrict__ Qg, const unsigned short* __restrict__ Kg,
    const unsigned short* __restrict__ Vtg, float* __restrict__ out) {
  extern __shared__ unsigned short sm[];
  unsigned short* Kl = sm;
  unsigned short* Vl = sm + 18432;
  const int tid = threadIdx.x;
  const int w = tid >> 6, lane = tid & 63, g = lane >> 4, q = lane & 15;
  const int b = blockIdx.x;
  const unsigned short* Kgb = Kg + (long)b * 16384;
  const unsigned short* Vgb = Vtg + (long)b * 16384;

  // stage K row-major (padded 72) and V^T h-major (padded 264)
#pragma unroll
  for (int it = 0; it < 4; ++it) {
    int i = tid + it * 512;
    int tok = i >> 3, k0 = (i & 7) * 8;
    *(uint4*)&Kl[tok * 72 + k0] = *(const uint4*)&Kgb[tok * 64 + k0];
  }
#pragma unroll
  for (int it = 0; it < 4; ++it) {
    int i = tid + it * 512;
    int hh = i >> 5, t0 = (i & 31) * 8;
    *(uint4*)&Vl[hh * 264 + t0] = *(const uint4*)&Vgb[hh * 256 + t0];
  }
  __syncthreads();

  unsigned short* Pb = sm + 35328 + w * 640;  // per-wave [16][40] P buffer
  const float SCL = 0.125f * 1.4426950408889634f;  // H^-0.5 * log2(e)
  const f32x4 zf = {0.f, 0.f, 0.f, 0.f};

#pragma unroll
  for (int ti = 0; ti < 2; ++ti) {
    const int t = ti ? (15 - w) : w;

    // Q as B-operand: lane (q,g) holds Q[b*256+16t+q][8g.. / 32+8g..]
    const unsigned short* Qrow = Qg + ((long)b * 256 + 16 * t + q) * 64;
    short8 aq0 = *(const short8*)&Qrow[g * 8];
    short8 aq1 = *(const short8*)&Qrow[32 + g * 8];

    f32x4 o[4];
#pragma unroll
    for (int ct = 0; ct < 4; ++ct) o[ct] = zf;
    float m = -1e30f;
    float lsum = 0.f;

    const int KS = (t >> 1) + 1;  // wave-uniform trip count
    for (int ks = 0; ks < KS; ++ks) {
      const int j0 = 2 * ks, j1 = 2 * ks + 1;
      const bool has1 = (j1 <= t);
      // K as A-operand: D[row=4g+jr][col=q] = S[K-token 16j+4g+jr][Q-row 16t+q]
      short8 ka0 = *(const short8*)&Kl[(16 * j0 + q) * 72 + g * 8];
      short8 ka1 = *(const short8*)&Kl[(16 * j0 + q) * 72 + 32 + g * 8];
      f32x4 s0 = MFMA16(ka0, aq0, zf);
      s0 = MFMA16(ka1, aq1, s0);
      f32x4 s1 = zf;
      if (has1) {
        short8 kb0 = *(const short8*)&Kl[(16 * j1 + q) * 72 + g * 8];
        short8 kb1 = *(const short8*)&Kl[(16 * j1 + q) * 72 + 32 + g * 8];
        s1 = MFMA16(kb0, aq0, zf);
        s1 = MFMA16(kb1, aq1, s1);
      }
      float v[8];
#pragma unroll
      for (int jr = 0; jr < 4; ++jr) {
        float aa = s0[jr] * SCL;
        if (j0 == t && 4 * g + jr > q) aa = -1e30f;  // causal (diag tile)
        v[jr] = aa;
        float cc = has1 ? s1[jr] * SCL : -1e30f;
        if (has1 && j1 == t && 4 * g + jr > q) cc = -1e30f;
        v[4 + jr] = cc;
      }
      float mloc = fmaxf(fmaxf(fmaxf(v[0], v[1]), fmaxf(v[2], v[3])),
                         fmaxf(fmaxf(v[4], v[5]), fmaxf(v[6], v[7])));
      mloc = fmaxf(mloc, __shfl_xor(mloc, 16));
      mloc = fmaxf(mloc, __shfl_xor(mloc, 32));
      float mnew = fmaxf(m, mloc);
      float f = exp2f(m - mnew);  // factor for q-row q (this lane's row)
      m = mnew;
      float p[8];
      float ls = 0.f;
#pragma unroll
      for (int i = 0; i < 8; ++i) { p[i] = exp2f(v[i] - mnew); ls += p[i]; }
      lsum = lsum * f + ls;
      // o[ct][jr] accumulates Q-row 4g+jr -> fetch that row's factor
#pragma unroll
      for (int jr = 0; jr < 4; ++jr) {
        float fr = __shfl(f, 4 * g + jr);
        o[0][jr] *= fr; o[1][jr] *= fr; o[2][jr] *= fr; o[3][jr] *= fr;
      }
      // P store (row q, cols 4g..4g+3 of each 16-tile) then transposed read
      uint2 pa; pa.x = f2bf2(p[0], p[1]); pa.y = f2bf2(p[2], p[3]);
      *(uint2*)&Pb[q * 40 + 4 * g] = pa;
      uint2 pc; pc.x = f2bf2(p[4], p[5]); pc.y = f2bf2(p[6], p[7]);
      *(uint2*)&Pb[q * 40 + 16 + 4 * g] = pc;
      short8 ap = *(const short8*)&Pb[q * 40 + g * 8];
#pragma unroll
      for (int ct = 0; ct < 4; ++ct) {
        short8 bv = *(const short8*)&Vl[(16 * ct + q) * 264 + ks * 32 + g * 8];
        o[ct] = MFMA16(ap, bv, o[ct]);
      }
    }

    // final row-sum: fold g-partials (row q), then fetch row 4g+jr's sum
    lsum += __shfl_xor(lsum, 16);
    lsum += __shfl_xor(lsum, 32);
    float linv[4];
#pragma unroll
    for (int jr = 0; jr < 4; ++jr) linv[jr] = 1.0f / __shfl(lsum, 4 * g + jr);

    const long rowbase = (long)b * 256 + 16 * t;
#pragma unroll
    for (int jr = 0; jr < 4; ++jr) {
#pragma unroll
      for (int ct = 0; ct < 4; ++ct) {
        out[(rowbase + 4 * g + jr) * 64 + 16 * ct + q] = o[ct][jr] * linv[jr];
      }
    }
  }
}

// ---------------------------------------------------------------------------
extern "C" void kernel_launch(void* const* d_in, const int* in_sizes, int n_in,
                              void* d_out, int out_size, void* d_ws, size_t ws_size,
                              hipStream_t stream) {
  const float* x  = (const float*)d_in[0];
  const float* Wq = (const float*)d_in[1];
  const float* Wk = (const float*)d_in[2];
  const float* Wv = (const float*)d_in[3];
  float* out = (float*)d_out;

  char* ws = (char*)d_ws;
  unsigned short* W3t = (unsigned short*)ws;                        // 147,456 B
  unsigned short* Qg  = (unsigned short*)(ws + 147456);             // 8,388,608 B
  unsigned short* Kg  = (unsigned short*)(ws + 147456 + 8388608);   // 8,388,608 B
  unsigned short* Vtg = (unsigned short*)(ws + 147456 + 16777216);  // 8,388,608 B

  hipFuncSetAttribute((const void*)attn_kernel,
                      hipFuncAttributeMaxDynamicSharedMemorySize, 80896);

  wconv_kernel<<<72, 128, 0, stream>>>(Wq, Wk, Wv, W3t);
  proj_kernel<<<512, 256, 0, stream>>>(x, W3t, Qg, Kg, Vtg);
  attn_kernel<<<256, 512, 80896, stream>>>(Qg, Kg, Vtg, out);
}